// Round 13
// baseline (270.944 us; speedup 1.0000x reference)
//
#include <hip/hip_runtime.h>
#include <hip/hip_bf16.h>

#define BB 8
#define NN 2048
#define DD 128

typedef __attribute__((ext_vector_type(8))) __bf16 bf16x8;
typedef __attribute__((ext_vector_type(4))) float f32x4;
typedef __attribute__((ext_vector_type(4))) int   i32x4;

static __device__ __forceinline__ unsigned short f2bf(float f) {
    union { float f; unsigned u; } v; v.f = f;
    unsigned r = (v.u + 0x7FFFu + ((v.u >> 16) & 1u)) >> 16;
    return (unsigned short)r;
}
static __device__ __forceinline__ float bf2f(unsigned short b) {
    union { unsigned u; float f; } v; v.u = ((unsigned)b) << 16;
    return v.f;
}

// ---------------------------------------------------------------------------
// kernBP: heterogeneous B0 || PACK (round-13).
// Evidence: the pack costs ~50-55us standalone in EVERY structure (R0/R5/R7/
// R10/R12) but cost only +21us (pure BW floor) when co-resident with other
// work (R3's kernF, pack between barrier arrival/wait). => latency-exposure-
// bound alone; full BW when overlapped. This kernel creates the co-residency:
//   bid <  256: B0 body (R11/R12-proven): si0 = x@Ws^T+b_self (unfolded),
//               yne0, yT0, aw. 40KB LDS.
//   bid >= 256: pack block (R3 loop structure + R0 epilogue, verbatim-
//               proven): packs rows [pb*64, pb*64+64) -> pk/scl/pdm global.
// 2 blocks/CU (80KB LDS) -> each CU runs ~4 GEMM waves + ~4 pack waves
// simultaneously; pack HBM latency hides under MFMA issue.
// ---------------------------------------------------------------------------
__global__ __launch_bounds__(256) void kernBP(
    const float* __restrict__ x,
    const int* __restrict__ punct, const int* __restrict__ mask,
    const float* __restrict__ w_nw, const float* __restrict__ b_nw,
    const float* __restrict__ w_self, const float* __restrict__ b_self,
    const float* __restrict__ w_punct,
    float* __restrict__ si_out,
    unsigned short* __restrict__ yne_out,   // [B*N][D] bf16
    unsigned short* __restrict__ yT_out,    // [B][D][N] bf16
    float* __restrict__ aw_out,
    unsigned* __restrict__ pk, float* __restrict__ scale_g,
    float* __restrict__ pdm_g)
{
    __shared__ unsigned short xt[64*32];
    __shared__ unsigned short wst[128*32];
    __shared__ unsigned short wpt[128*32];
    __shared__ float wnw_l[DD];
    __shared__ float red[256];
    __shared__ float dw_l[64];
    __shared__ unsigned short ytl[128*72];

    const int bid = blockIdx.x;
    const int t   = threadIdx.x;

    if (bid >= 256) {
        // ---- PACK block: rows [pb*64, pb*64+64), 16 rows per wave ----
        const int pb   = bid - 256;
        const int wave = t >> 6, lane = t & 63;
        const int b    = (pb * 64) >> 11;           // block-uniform batch
        const int* mrow = mask + (size_t)b * NN;

        int mv[32];
        #pragma unroll
        for (int w = 0; w < 32; ++w) mv[w] = mrow[w * 64 + lane];

        for (int rr = 0; rr < 16; ++rr) {
            const int row_g = pb * 64 + wave * 16 + rr;
            const int i = row_g & (NN - 1);         // diagonal column
            const int* prow = punct + (size_t)row_g * NN;
            unsigned p0 = 0, p1 = 0;
            int acc = 0;
            #pragma unroll
            for (int h = 0; h < 2; ++h) {
                int pv[16];
                #pragma unroll
                for (int w = 0; w < 16; ++w)
                    pv[w] = prow[(h * 16 + w) * 64 + lane];
                #pragma unroll
                for (int w = 0; w < 16; ++w) {
                    const int wg = h * 16 + w;
                    const int pred = (pv[w] & mv[wg]) & 1;
                    unsigned long long bal = __ballot(pred);
                    if (lane == wg) { p0 = (unsigned)bal; p1 = (unsigned)(bal >> 32); }
                    acc += pred + (((wg * 64 + lane) == i ? pred : 0) << 16);
                }
            }
            #pragma unroll
            for (int o = 32; o > 0; o >>= 1) acc += __shfl_xor(acc, o, 64);
            if (lane < 32) {
                uint2 w2; w2.x = p0; w2.y = p1;
                *(uint2*)(pk + (size_t)row_g * 64 + 2 * lane) = w2;
            }
            if (lane == 0) {
                const int nall = acc & 0xFFFF;
                const int pd   = acc >> 16;         // masked diagonal
                const int mi   = mrow[i];
                const int nbr  = nall - pd;
                scale_g[row_g] = mi ? 1.f / (float)(nbr < 1 ? 1 : nbr) : 0.f;
                pdm_g[row_g]   = (float)pd;
            }
        }
        return;
    }

    // ---- B0 body (R11/R12-proven, verbatim) ----
    const int n0 = bid * 64;
    const int b  = n0 >> 11;
    const int nb = n0 & (NN - 1);

    if (t < DD) wnw_l[t] = w_nw[t];
    __syncthreads();

    const int wave = t >> 6, lane = t & 63;
    const int wm = wave >> 1, wn = wave & 1;
    const int quad = lane >> 4, l16 = lane & 15;

    const int n_loc = t >> 2, dq = t & 3;
    const int we = t >> 1,   wh = t & 1;

    f32x4 accs[2][4] = {}; f32x4 accp[2][4] = {};
    float dwpart = 0.f;

    #pragma unroll
    for (int kk = 0; kk < 4; ++kk) {
        const int k0 = kk * 32;
        {
            const float* xs = x + (size_t)(n0 + n_loc) * DD + k0 + dq * 8;
            f32x4 a = *(const f32x4*)xs;
            f32x4 c = *(const f32x4*)(xs + 4);
            const float* wv = &wnw_l[k0 + dq * 8];
            dwpart += a.x*wv[0] + a.y*wv[1] + a.z*wv[2] + a.w*wv[3]
                    + c.x*wv[4] + c.y*wv[5] + c.z*wv[6] + c.w*wv[7];
            unsigned q0 = f2bf(a.x) | ((unsigned)f2bf(a.y) << 16);
            unsigned q1 = f2bf(a.z) | ((unsigned)f2bf(a.w) << 16);
            unsigned q2 = f2bf(c.x) | ((unsigned)f2bf(c.y) << 16);
            unsigned q3 = f2bf(c.z) | ((unsigned)f2bf(c.w) << 16);
            i32x4 pw = {(int)q0,(int)q1,(int)q2,(int)q3};
            *(i32x4*)&xt[n_loc*32 + dq*8] = pw;
        }
        {
            const float* s1 = w_self  + (size_t)we * DD + k0 + wh*16;
            const float* s2 = w_punct + (size_t)we * DD + k0 + wh*16;
            f32x4 a0 = *(const f32x4*)s1;      f32x4 a1 = *(const f32x4*)(s1+4);
            f32x4 a2 = *(const f32x4*)(s1+8);  f32x4 a3 = *(const f32x4*)(s1+12);
            unsigned q0 = f2bf(a0.x) | ((unsigned)f2bf(a0.y)<<16);
            unsigned q1 = f2bf(a0.z) | ((unsigned)f2bf(a0.w)<<16);
            unsigned q2 = f2bf(a1.x) | ((unsigned)f2bf(a1.y)<<16);
            unsigned q3 = f2bf(a1.z) | ((unsigned)f2bf(a1.w)<<16);
            unsigned q4 = f2bf(a2.x) | ((unsigned)f2bf(a2.y)<<16);
            unsigned q5 = f2bf(a2.z) | ((unsigned)f2bf(a2.w)<<16);
            unsigned q6 = f2bf(a3.x) | ((unsigned)f2bf(a3.y)<<16);
            unsigned q7 = f2bf(a3.z) | ((unsigned)f2bf(a3.w)<<16);
            i32x4 pw0 = {(int)q0,(int)q1,(int)q2,(int)q3};
            i32x4 pw1 = {(int)q4,(int)q5,(int)q6,(int)q7};
            *(i32x4*)&wst[we*32 + wh*16]     = pw0;
            *(i32x4*)&wst[we*32 + wh*16 + 8] = pw1;
            f32x4 c0 = *(const f32x4*)s2;      f32x4 c1 = *(const f32x4*)(s2+4);
            f32x4 c2 = *(const f32x4*)(s2+8);  f32x4 c3 = *(const f32x4*)(s2+12);
            unsigned r0 = f2bf(c0.x) | ((unsigned)f2bf(c0.y)<<16);
            unsigned r1 = f2bf(c0.z) | ((unsigned)f2bf(c0.w)<<16);
            unsigned r2 = f2bf(c1.x) | ((unsigned)f2bf(c1.y)<<16);
            unsigned r3 = f2bf(c1.z) | ((unsigned)f2bf(c1.w)<<16);
            unsigned r4 = f2bf(c2.x) | ((unsigned)f2bf(c2.y)<<16);
            unsigned r5 = f2bf(c2.z) | ((unsigned)f2bf(c2.w)<<16);
            unsigned r6 = f2bf(c3.x) | ((unsigned)f2bf(c3.y)<<16);
            unsigned r7 = f2bf(c3.z) | ((unsigned)f2bf(c3.w)<<16);
            i32x4 pv0 = {(int)r0,(int)r1,(int)r2,(int)r3};
            i32x4 pv1 = {(int)r4,(int)r5,(int)r6,(int)r7};
            *(i32x4*)&wpt[we*32 + wh*16]     = pv0;
            *(i32x4*)&wpt[we*32 + wh*16 + 8] = pv1;
        }
        __syncthreads();
        bf16x8 af[2], bs[4], bp[4];
        #pragma unroll
        for (int mt = 0; mt < 2; ++mt)
            af[mt] = *(const bf16x8*)&xt[(wm*32 + mt*16 + l16)*32 + quad*8];
        #pragma unroll
        for (int nt = 0; nt < 4; ++nt) {
            const int er = wn*64 + nt*16 + l16;
            bs[nt] = *(const bf16x8*)&wst[er*32 + quad*8];
            bp[nt] = *(const bf16x8*)&wpt[er*32 + quad*8];
        }
        #pragma unroll
        for (int mt = 0; mt < 2; ++mt)
            #pragma unroll
            for (int nt = 0; nt < 4; ++nt) {
                accs[mt][nt] = __builtin_amdgcn_mfma_f32_16x16x32_bf16(af[mt], bs[nt], accs[mt][nt], 0, 0, 0);
                accp[mt][nt] = __builtin_amdgcn_mfma_f32_16x16x32_bf16(af[mt], bp[nt], accp[mt][nt], 0, 0, 0);
            }
        __syncthreads();
    }

    red[t] = dwpart;
    __syncthreads();
    if (t < 64) {
        float s = red[4*t] + red[4*t+1] + red[4*t+2] + red[4*t+3] + b_nw[0];
        float dv = 1.f / (1.f + __expf(-s));
        dw_l[t] = dv;
        aw_out[(size_t)b * 2 * NN + nb + t] = dv;
    }
    __syncthreads();

    #pragma unroll
    for (int mt = 0; mt < 2; ++mt) {
        #pragma unroll
        for (int nt = 0; nt < 4; ++nt) {
            const int e = wn*64 + nt*16 + l16;
            const float bsv = b_self[e];
            #pragma unroll
            for (int r = 0; r < 4; ++r) {
                const int nl = wm*32 + mt*16 + quad*4 + r;
                const size_t idx = (size_t)(n0 + nl) * DD + e;
                si_out[idx] = accs[mt][nt][r] + bsv;
                const float yv = dw_l[nl] * accp[mt][nt][r];
                const unsigned short ub = f2bf(yv);
                yne_out[idx] = ub;
                ytl[e*72 + nl] = ub;
            }
        }
    }
    __syncthreads();
    {
        const int e = t >> 1, half = t & 1;
        const i32x4* src = (const i32x4*)&ytl[e*72 + half*32];
        i32x4 v0 = src[0], v1 = src[1], v2 = src[2], v3 = src[3];
        i32x4* dst = (i32x4*)(yT_out + (size_t)(b*DD + e) * NN + nb + half*32);
        dst[0] = v0; dst[1] = v1; dst[2] = v2; dst[3] = v3;
    }
}

// ---------------------------------------------------------------------------
// kernCB (R11-proven, verbatim): FUSED C0 + B1. C-phase: unfolded diag via
// yne0; B-phase: f32 weight conversion in staging, diag-folded si'1, yT1, aw1.
// ---------------------------------------------------------------------------
#define OFF_SCL   0u
#define OFF_PDM   256u
#define OFF_WNW   512u
#define OFF_DW    1024u
#define OFF_A     1280u
#define OFF_XT4   1280u
#define OFF_RED   (1280u + 16384u)
#define OFF_B     25856u
#define OFF_WST   25856u
#define OFF_WPT   (25856u + 8192u)
#define OFF_YTL   (25856u + 16384u)
#define SMEM_CB   60672u

__global__ __launch_bounds__(256) void kernCB(
    const unsigned* __restrict__ pk,
    const float* __restrict__ scale_g, const float* __restrict__ pdm_g,
    const unsigned short* __restrict__ yT0,
    const unsigned short* __restrict__ yne0,
    float* si,                               // in: si0 ; out: si'1 (folded)
    const float* __restrict__ w_self, const float* __restrict__ w_punct,
    const float* __restrict__ w_nw, const float* __restrict__ b_nw,
    const float* __restrict__ b_self,
    unsigned short* __restrict__ yT1,
    float* __restrict__ aw1)
{
    __shared__ char smem[SMEM_CB];
    float*          scl_l = (float*)(smem + OFF_SCL);
    float*          pdm_l = (float*)(smem + OFF_PDM);
    float*          wnw_l = (float*)(smem + OFF_WNW);
    float*          dw_l  = (float*)(smem + OFF_DW);
    unsigned*       pPk   = (unsigned*)(smem + OFF_A);
    unsigned short* xt4   = (unsigned short*)(smem + OFF_XT4);
    float*          red   = (float*)(smem + OFF_RED);
    f32x4*          accL  = (f32x4*)(smem + OFF_B);
    unsigned short* wst   = (unsigned short*)(smem + OFF_WST);
    unsigned short* wpt   = (unsigned short*)(smem + OFF_WPT);
    unsigned short* ytl   = (unsigned short*)(smem + OFF_YTL);

    const int t  = threadIdx.x;
    const int b  = blockIdx.x & 7;
    const int i0 = (blockIdx.x >> 3) * 64;
    const size_t rg0 = (size_t)b * NN + i0;

    #pragma unroll
    for (int r = 0; r < 4; ++r) {
        const int u   = r * 256 + t;
        const int row = u >> 4;
        const int wq  = (u & 15) * 4;
        i32x4 v = *(const i32x4*)(pk + (rg0 + row) * 64 + wq);
        *(i32x4*)&pPk[row * 68 + wq] = v;
    }
    if (t < 64)                   scl_l[t]      = scale_g[rg0 + t];
    else if (t < 128)             pdm_l[t-64]   = pdm_g[rg0 + t - 64];
    else                          wnw_l[t-128]  = w_nw[t-128];
    __syncthreads();

    const int wave = t >> 6, lane = t & 63;
    const int kh = wave >> 1, eh = wave & 1;
    const int quad = lane >> 4, l16 = lane & 15;
    const unsigned short* yTb = yT0 + (size_t)b * DD * NN;

    f32x4 acc[4][4] = {};
    #pragma unroll 4
    for (int ks = 0; ks < 32; ++ks) {
        const int kk = kh * 32 + ks;
        bf16x8 bfr[4];
        #pragma unroll
        for (int nt = 0; nt < 4; ++nt) {
            const int e = eh*64 + nt*16 + l16;
            bfr[nt] = *(const bf16x8*)(yTb + (size_t)e * NN + kk*32 + quad*8);
        }
        bf16x8 af[4];
        #pragma unroll
        for (int mt = 0; mt < 4; ++mt) {
            const unsigned w = pPk[(mt*16 + l16) * 68 + kk];
            const unsigned by = (w >> (quad * 8)) & 0xFFu;
            i32x4 ex;
            ex.x = (int)((((by &   1u) << 7) + ((by &   2u) << 22)) * 0x7Fu);
            ex.y = (int)((((by &   4u) << 5) + ((by &   8u) << 20)) * 0x7Fu);
            ex.z = (int)((((by &  16u) << 3) + ((by &  32u) << 18)) * 0x7Fu);
            ex.w = (int)((((by &  64u) << 1) + ((by & 128u) << 16)) * 0x7Fu);
            union { i32x4 i; bf16x8 h; } cv; cv.i = ex;
            af[mt] = cv.h;
        }
        #pragma unroll
        for (int mt = 0; mt < 4; ++mt)
            #pragma unroll
            for (int nt = 0; nt < 4; ++nt)
                acc[mt][nt] = __builtin_amdgcn_mfma_f32_16x16x32_bf16(af[mt], bfr[nt], acc[mt][nt], 0, 0, 0);
    }

    __syncthreads();
    if (kh == 1) {
        #pragma unroll
        for (int mt = 0; mt < 4; ++mt)
            #pragma unroll
            for (int nt = 0; nt < 4; ++nt)
                accL[(eh*16 + mt*4 + nt)*64 + lane] = acc[mt][nt];
    }
    __syncthreads();

    if (kh == 0) {
        #pragma unroll
        for (int mt = 0; mt < 4; ++mt) {
            float part[4] = {0.f, 0.f, 0.f, 0.f};
            #pragma unroll
            for (int nt = 0; nt < 4; ++nt) {
                f32x4 o = accL[(eh*16 + mt*4 + nt)*64 + lane];
                const int e = eh*64 + nt*16 + l16;
                const float wv = wnw_l[e];
                #pragma unroll
                for (int r = 0; r < 4; ++r) {
                    const int row = mt*16 + quad*4 + r;
                    const size_t idx = (rg0 + row) * DD + e;
                    const float yv = bf2f(yne0[idx]);
                    float xv = si[idx]
                             + scl_l[row] * (acc[mt][nt][r] + o[r] - pdm_l[row] * yv);
                    xv = fmaxf(xv, 0.f);
                    xt4[((e >> 5) * 64 + row) * 32 + (e & 31)] = f2bf(xv);
                    part[r] += xv * wv;
                }
            }
            #pragma unroll
            for (int r = 0; r < 4; ++r) {
                const int row = mt*16 + quad*4 + r;
                red[row * 32 + eh*16 + l16] = part[r];
            }
        }
    }
    __syncthreads();

    if (t < 64) {
        float s = b_nw[0];
        #pragma unroll 8
        for (int c = 0; c < 32; ++c) s += red[t * 32 + c];
        float dv = 1.f / (1.f + __expf(-s));
        dw_l[t] = dv;
        aw1[(size_t)b * 2 * NN + i0 + t] = dv;
    }
    __syncthreads();

    const int wm = kh, wn = eh;
    const int we = t >> 1, wh = t & 1;

    f32x4 accs[2][4] = {}; f32x4 accp[2][4] = {};

    #pragma unroll
    for (int kk = 0; kk < 4; ++kk) {
        const int k0 = kk * 32;
        {
            const float* s1 = w_self  + (size_t)we * DD + k0 + wh*16;
            const float* s2 = w_punct + (size_t)we * DD + k0 + wh*16;
            f32x4 a0 = *(const f32x4*)s1;      f32x4 a1 = *(const f32x4*)(s1+4);
            f32x4 a2 = *(const f32x4*)(s1+8);  f32x4 a3 = *(const f32x4*)(s1+12);
            unsigned q0 = f2bf(a0.x) | ((unsigned)f2bf(a0.y)<<16);
            unsigned q1 = f2bf(a0.z) | ((unsigned)f2bf(a0.w)<<16);
            unsigned q2 = f2bf(a1.x) | ((unsigned)f2bf(a1.y)<<16);
            unsigned q3 = f2bf(a1.z) | ((unsigned)f2bf(a1.w)<<16);
            unsigned q4 = f2bf(a2.x) | ((unsigned)f2bf(a2.y)<<16);
            unsigned q5 = f2bf(a2.z) | ((unsigned)f2bf(a2.w)<<16);
            unsigned q6 = f2bf(a3.x) | ((unsigned)f2bf(a3.y)<<16);
            unsigned q7 = f2bf(a3.z) | ((unsigned)f2bf(a3.w)<<16);
            i32x4 pw0 = {(int)q0,(int)q1,(int)q2,(int)q3};
            i32x4 pw1 = {(int)q4,(int)q5,(int)q6,(int)q7};
            *(i32x4*)&wst[we*32 + wh*16]     = pw0;
            *(i32x4*)&wst[we*32 + wh*16 + 8] = pw1;
            f32x4 c0 = *(const f32x4*)s2;      f32x4 c1 = *(const f32x4*)(s2+4);
            f32x4 c2 = *(const f32x4*)(s2+8);  f32x4 c3 = *(const f32x4*)(s2+12);
            unsigned r0 = f2bf(c0.x) | ((unsigned)f2bf(c0.y)<<16);
            unsigned r1 = f2bf(c0.z) | ((unsigned)f2bf(c0.w)<<16);
            unsigned r2 = f2bf(c1.x) | ((unsigned)f2bf(c1.y)<<16);
            unsigned r3 = f2bf(c1.z) | ((unsigned)f2bf(c1.w)<<16);
            unsigned r4 = f2bf(c2.x) | ((unsigned)f2bf(c2.y)<<16);
            unsigned r5 = f2bf(c2.z) | ((unsigned)f2bf(c2.w)<<16);
            unsigned r6 = f2bf(c3.x) | ((unsigned)f2bf(c3.y)<<16);
            unsigned r7 = f2bf(c3.z) | ((unsigned)f2bf(c3.w)<<16);
            i32x4 pv0 = {(int)r0,(int)r1,(int)r2,(int)r3};
            i32x4 pv1 = {(int)r4,(int)r5,(int)r6,(int)r7};
            *(i32x4*)&wpt[we*32 + wh*16]     = pv0;
            *(i32x4*)&wpt[we*32 + wh*16 + 8] = pv1;
        }
        __syncthreads();
        bf16x8 af[2], bs[4], bp[4];
        #pragma unroll
        for (int mt = 0; mt < 2; ++mt)
            af[mt] = *(const bf16x8*)&xt4[(kk*64 + wm*32 + mt*16 + l16)*32 + quad*8];
        #pragma unroll
        for (int nt = 0; nt < 4; ++nt) {
            const int er = wn*64 + nt*16 + l16;
            bs[nt] = *(const bf16x8*)&wst[er*32 + quad*8];
            bp[nt] = *(const bf16x8*)&wpt[er*32 + quad*8];
        }
        #pragma unroll
        for (int mt = 0; mt < 2; ++mt)
            #pragma unroll
            for (int nt = 0; nt < 4; ++nt) {
                accs[mt][nt] = __builtin_amdgcn_mfma_f32_16x16x32_bf16(af[mt], bs[nt], accs[mt][nt], 0, 0, 0);
                accp[mt][nt] = __builtin_amdgcn_mfma_f32_16x16x32_bf16(af[mt], bp[nt], accp[mt][nt], 0, 0, 0);
            }
        __syncthreads();
    }

    #pragma unroll
    for (int mt = 0; mt < 2; ++mt) {
        #pragma unroll
        for (int nt = 0; nt < 4; ++nt) {
            const int e = wn*64 + nt*16 + l16;
            const float bsv = b_self[e];
            #pragma unroll
            for (int r = 0; r < 4; ++r) {
                const int nl = wm*32 + mt*16 + quad*4 + r;
                const size_t idx = (rg0 + nl) * DD + e;
                const float yv = dw_l[nl] * accp[mt][nt][r];
                const unsigned short ub = f2bf(yv);
                const float yvr = bf2f(ub);
                si[idx] = accs[mt][nt][r] + bsv - scl_l[nl] * pdm_l[nl] * yvr;
                ytl[e*72 + nl] = ub;
            }
        }
    }
    __syncthreads();
    {
        const int e = t >> 1, half = t & 1;
        const i32x4* src = (const i32x4*)&ytl[e*72 + half*32];
        i32x4 v0 = src[0], v1 = src[1], v2 = src[2], v3 = src[3];
        i32x4* dst = (i32x4*)(yT1 + (size_t)(b*DD + e) * NN + i0 + half*32);
        dst[0] = v0; dst[1] = v1; dst[2] = v2; dst[3] = v3;
    }
}

// ---------------------------------------------------------------------------
// kernC4 (R9-proven, verbatim): final C — x_out = relu(si'1 + scale*agg).
// ---------------------------------------------------------------------------
__global__ __launch_bounds__(256) void kernC4(
    const unsigned* __restrict__ pk,
    const float* __restrict__ scale_g,
    const unsigned short* __restrict__ yT,
    const float* __restrict__ sip,
    float* __restrict__ x_out)
{
    __shared__ unsigned pPk[64 * 68];
    __shared__ float scale_l[64];
    __shared__ f32x4 accL[2][16][64];

    const int t  = threadIdx.x;
    const int b  = blockIdx.x & 7;
    const int i0 = (blockIdx.x >> 3) * 64;
    const size_t rg0 = (size_t)b * NN + i0;

    #pragma unroll
    for (int r = 0; r < 4; ++r) {
        const int u   = r * 256 + t;
        const int row = u >> 4;
        const int wq  = (u & 15) * 4;
        i32x4 v = *(const i32x4*)(pk + (rg0 + row) * 64 + wq);
        *(i32x4*)&pPk[row * 68 + wq] = v;
    }
    if (t < 64) scale_l[t] = scale_g[rg0 + t];
    __syncthreads();

    const int wave = t >> 6, lane = t & 63;
    const int kh = wave >> 1, eh = wave & 1;
    const int quad = lane >> 4, l16 = lane & 15;
    const unsigned short* yTb = yT + (size_t)b * DD * NN;

    f32x4 acc[4][4] = {};

    #pragma unroll 4
    for (int ks = 0; ks < 32; ++ks) {
        const int kk = kh * 32 + ks;
        bf16x8 bfr[4];
        #pragma unroll
        for (int nt = 0; nt < 4; ++nt) {
            const int e = eh*64 + nt*16 + l16;
            bfr[nt] = *(const bf16x8*)(yTb + (size_t)e * NN + kk*32 + quad*8);
        }
        bf16x8 af[4];
        #pragma unroll
        for (int mt = 0; mt < 4; ++mt) {
            const unsigned w = pPk[(mt*16 + l16) * 68 + kk];
            const unsigned by = (w >> (quad * 8)) & 0xFFu;
            i32x4 ex;
            ex.x = (int)((((by &   1u) << 7) + ((by &   2u) << 22)) * 0x7Fu);
            ex.y = (int)((((by &   4u) << 5) + ((by &   8u) << 20)) * 0x7Fu);
            ex.z = (int)((((by &  16u) << 3) + ((by &  32u) << 18)) * 0x7Fu);
            ex.w = (int)((((by &  64u) << 1) + ((by & 128u) << 16)) * 0x7Fu);
            union { i32x4 i; bf16x8 h; } cv; cv.i = ex;
            af[mt] = cv.h;
        }
        #pragma unroll
        for (int mt = 0; mt < 4; ++mt)
            #pragma unroll
            for (int nt = 0; nt < 4; ++nt)
                acc[mt][nt] = __builtin_amdgcn_mfma_f32_16x16x32_bf16(af[mt], bfr[nt], acc[mt][nt], 0, 0, 0);
    }

    __syncthreads();
    if (kh == 1) {
        #pragma unroll
        for (int mt = 0; mt < 4; ++mt)
            #pragma unroll
            for (int nt = 0; nt < 4; ++nt)
                accL[eh][mt*4 + nt][lane] = acc[mt][nt];
    }
    __syncthreads();
    if (kh == 0) {
        #pragma unroll
        for (int mt = 0; mt < 4; ++mt) {
            #pragma unroll
            for (int nt = 0; nt < 4; ++nt) {
                f32x4 o = accL[eh][mt*4 + nt][lane];
                const int e = eh*64 + nt*16 + l16;
                #pragma unroll
                for (int r = 0; r < 4; ++r) {
                    const int row = mt*16 + quad*4 + r;
                    const size_t idx = (rg0 + row) * DD + e;
                    float v = sip[idx] + scale_l[row] * (acc[mt][nt][r] + o[r]);
                    x_out[idx] = fmaxf(v, 0.f);
                }
            }
        }
    }
}

extern "C" void kernel_launch(void* const* d_in, const int* in_sizes, int n_in,
                              void* d_out, int out_size, void* d_ws, size_t ws_size,
                              hipStream_t stream) {
    const float* node   = (const float*)d_in[0];
    const int*   mask   = (const int*)  d_in[1];
    const int*   punct  = (const int*)  d_in[2];
    const float* w_nw   = (const float*)d_in[3];
    const float* b_nw   = (const float*)d_in[4];
    const float* w_self = (const float*)d_in[5];
    const float* b_self = (const float*)d_in[6];
    const float* w_punct= (const float*)d_in[7];

    float* xout = (float*)d_out;
    float* aw   = xout + (size_t)BB * NN * DD;

    char* w = (char*)d_ws;
    float*          si   = (float*)w;                               // 8 MB
    unsigned short* yne0 = (unsigned short*)(w + (8u  << 20));      // 4 MB
    unsigned short* yT0  = (unsigned short*)(w + (12u << 20));      // 4 MB
    unsigned*       pk   = (unsigned*)(w + (16u << 20));            // 4 MB
    float*          scl  = (float*)(w + (20u << 20));               // 64 KB
    float*          pdm  = (float*)(w + (20u << 20) + (64u << 10)); // 64 KB
    unsigned short* yT1  = (unsigned short*)(w + (24u << 20));      // 4 MB

    kernBP<<<dim3(512), dim3(256), 0, stream>>>(node, punct, mask,
                                                w_nw, b_nw, w_self, b_self,
                                                w_punct, si, yne0, yT0, aw,
                                                pk, scl, pdm);
    kernCB<<<dim3(256), dim3(256), 0, stream>>>(pk, scl, pdm, yT0, yne0, si,
                                                w_self, w_punct, w_nw, b_nw,
                                                b_self, yT1, aw + NN);
    kernC4<<<dim3(256), dim3(256), 0, stream>>>(pk, scl, yT1, si, xout);
}

// Round 14
// 257.059 us; speedup vs baseline: 1.0540x; 1.0540x over previous
//
#include <hip/hip_runtime.h>
#include <hip/hip_bf16.h>

#define BB 8
#define NN 2048
#define DD 128

typedef __attribute__((ext_vector_type(8))) __bf16 bf16x8;
typedef __attribute__((ext_vector_type(4))) float f32x4;
typedef __attribute__((ext_vector_type(4))) int   i32x4;

static __device__ __forceinline__ unsigned short f2bf(float f) {
    union { float f; unsigned u; } v; v.f = f;
    unsigned r = (v.u + 0x7FFFu + ((v.u >> 16) & 1u)) >> 16;
    return (unsigned short)r;
}
static __device__ __forceinline__ float bf2f(unsigned short b) {
    union { unsigned u; float f; } v; v.u = ((unsigned)b) << 16;
    return v.f;
}

// ---------------------------------------------------------------------------
// FINAL (revert to R9, the measured-best 258.9us configuration).
// Ledger: fills 156 (harness) + P 52 (at the ~2.6TB/s empirical input-read
// ceiling — six pack structures all measured ~50-60us) + B0 16 + CB 22 +
// C4 10. Pipeline: P3 -> B(diag-folded) -> CB(fused C0+B1) -> C4.
// ---------------------------------------------------------------------------

// kernP3: Ptilde bit-pack with row-skip + word-per-lane.
// Blocks >= 2048: weight f32->bf16 conversion.
__global__ __launch_bounds__(256) void kernP3(
    const int* __restrict__ punct, const int* __restrict__ mask,
    const float* __restrict__ w_self, const float* __restrict__ w_punct,
    unsigned* __restrict__ pk, float* __restrict__ scale_g, float* __restrict__ pdm_g,
    unsigned short* __restrict__ wsb, unsigned short* __restrict__ wpb)
{
    const int bid = blockIdx.x;
    const int t = threadIdx.x;

    if (bid >= 2048) {   // weight conversion tail
        const int cb = bid - 2048;
        const float* src = (cb < 8) ? w_self : w_punct;
        unsigned short* dst = (cb < 8) ? wsb : wpb;
        const size_t i0 = (size_t)(cb & 7) * 2048 + (size_t)t * 8;
        f32x4 a = *(const f32x4*)(src + i0);
        f32x4 c = *(const f32x4*)(src + i0 + 4);
        unsigned q0 = f2bf(a.x) | ((unsigned)f2bf(a.y) << 16);
        unsigned q1 = f2bf(a.z) | ((unsigned)f2bf(a.w) << 16);
        unsigned q2 = f2bf(c.x) | ((unsigned)f2bf(c.y) << 16);
        unsigned q3 = f2bf(c.z) | ((unsigned)f2bf(c.w) << 16);
        i32x4 pw = {(int)q0, (int)q1, (int)q2, (int)q3};
        *(i32x4*)(dst + i0) = pw;
        return;
    }

    const int wave = t >> 6, lane = t & 63;
    const int row0 = bid * 8 + wave * 2;            // 2 rows per wave
    const int b = row0 >> 11;
    const int* mrow = mask + (size_t)b * NN;

    unsigned mw = 0;
    #pragma unroll
    for (int q = 0; q < 8; ++q) {
        i32x4 m = *(const i32x4*)(mrow + lane * 32 + q * 4);
        unsigned nib = (m.x & 1) | ((m.y & 1) << 1) | ((m.z & 1) << 2) | ((m.w & 1) << 3);
        mw |= nib << (4 * q);
    }

    #pragma unroll
    for (int r = 0; r < 2; ++r) {
        const int row = row0 + r;
        const int i = row & (NN - 1);               // diagonal column
        const int mi = mrow[i];                     // wave-uniform
        if (mi == 0) {                              // ROW SKIP (content dead)
            if (lane == 0) { scale_g[row] = 0.f; pdm_g[row] = 0.f; }
            continue;
        }
        const int* prow = punct + (size_t)row * NN;
        i32x4 v[8];
        #pragma unroll
        for (int q = 0; q < 8; ++q)
            v[q] = *(const i32x4*)(prow + lane * 32 + q * 4);
        unsigned wd = 0;
        #pragma unroll
        for (int q = 0; q < 8; ++q) {
            unsigned nib = (v[q].x & 1) | ((v[q].y & 1) << 1)
                         | ((v[q].z & 1) << 2) | ((v[q].w & 1) << 3);
            wd |= nib << (4 * q);
        }
        wd &= mw;
        pk[(size_t)row * 64 + lane] = wd;

        int acc = __popc(wd);
        if ((i >> 5) == lane) acc += (int)((wd >> (i & 31)) & 1u) << 16;
        #pragma unroll
        for (int o = 32; o > 0; o >>= 1) acc += __shfl_xor(acc, o, 64);
        if (lane == 0) {
            const int nall = acc & 0xFFFF;
            const int pd   = acc >> 16;
            const int nbr  = nall - pd;
            scale_g[row] = 1.f / (float)(nbr < 1 ? 1 : nbr);
            pdm_g[row]   = (float)pd;
        }
    }
}

// kernB: step-0 B with diag fold.
// si' = x@Ws^T + b_self - scale*pdm*round_bf16(yhat); yT0; aw.
__global__ __launch_bounds__(256) void kernB(
    const float* __restrict__ x,
    const unsigned short* __restrict__ wsb, const unsigned short* __restrict__ wpb,
    const float* __restrict__ w_nw, const float* __restrict__ b_nw,
    const float* __restrict__ b_self,
    const float* __restrict__ scale_g, const float* __restrict__ pdm_g,
    float* __restrict__ si_out, unsigned short* __restrict__ yT_out,
    float* __restrict__ aw_out)
{
    __shared__ unsigned short xt[64*32];
    __shared__ unsigned short wst[128*32];
    __shared__ unsigned short wpt[128*32];
    __shared__ float wnw_l[DD];
    __shared__ float red[256];
    __shared__ float dw_l[64];
    __shared__ float scl_l[64];
    __shared__ float pdm_l[64];
    __shared__ unsigned short ytl[128*72];

    const int n0 = blockIdx.x * 64;
    const int t  = threadIdx.x;
    const int b  = n0 >> 11;
    const int nb = n0 & (NN - 1);

    if (t < DD) wnw_l[t] = w_nw[t];
    if (t >= 128 && t < 192) { scl_l[t-128] = scale_g[n0 + t - 128]; }
    if (t >= 192)            { pdm_l[t-192] = pdm_g[n0 + t - 192]; }
    __syncthreads();

    const int wave = t >> 6, lane = t & 63;
    const int wm = wave >> 1, wn = wave & 1;
    const int quad = lane >> 4, l16 = lane & 15;

    const int n_loc = t >> 2, dq = t & 3;
    const int we = t >> 1,   wh = t & 1;

    f32x4 accs[2][4] = {}; f32x4 accp[2][4] = {};
    float dwpart = 0.f;

    #pragma unroll
    for (int kk = 0; kk < 4; ++kk) {
        const int k0 = kk * 32;
        {
            const float* xs = x + (size_t)(n0 + n_loc) * DD + k0 + dq * 8;
            f32x4 a = *(const f32x4*)xs;
            f32x4 c = *(const f32x4*)(xs + 4);
            const float* wv = &wnw_l[k0 + dq * 8];
            dwpart += a.x*wv[0] + a.y*wv[1] + a.z*wv[2] + a.w*wv[3]
                    + c.x*wv[4] + c.y*wv[5] + c.z*wv[6] + c.w*wv[7];
            unsigned q0 = f2bf(a.x) | ((unsigned)f2bf(a.y) << 16);
            unsigned q1 = f2bf(a.z) | ((unsigned)f2bf(a.w) << 16);
            unsigned q2 = f2bf(c.x) | ((unsigned)f2bf(c.y) << 16);
            unsigned q3 = f2bf(c.z) | ((unsigned)f2bf(c.w) << 16);
            i32x4 pw = {(int)q0,(int)q1,(int)q2,(int)q3};
            *(i32x4*)&xt[n_loc*32 + dq*8] = pw;
        }
        {
            const unsigned short* s1 = wsb + (size_t)we * DD + k0 + wh*16;
            const unsigned short* s2 = wpb + (size_t)we * DD + k0 + wh*16;
            i32x4 a0 = *(const i32x4*)s1;
            i32x4 a1 = *(const i32x4*)(s1 + 8);
            *(i32x4*)&wst[we*32 + wh*16]     = a0;
            *(i32x4*)&wst[we*32 + wh*16 + 8] = a1;
            i32x4 c0 = *(const i32x4*)s2;
            i32x4 c1 = *(const i32x4*)(s2 + 8);
            *(i32x4*)&wpt[we*32 + wh*16]     = c0;
            *(i32x4*)&wpt[we*32 + wh*16 + 8] = c1;
        }
        __syncthreads();
        bf16x8 af[2], bs[4], bp[4];
        #pragma unroll
        for (int mt = 0; mt < 2; ++mt)
            af[mt] = *(const bf16x8*)&xt[(wm*32 + mt*16 + l16)*32 + quad*8];
        #pragma unroll
        for (int nt = 0; nt < 4; ++nt) {
            const int er = wn*64 + nt*16 + l16;
            bs[nt] = *(const bf16x8*)&wst[er*32 + quad*8];
            bp[nt] = *(const bf16x8*)&wpt[er*32 + quad*8];
        }
        #pragma unroll
        for (int mt = 0; mt < 2; ++mt)
            #pragma unroll
            for (int nt = 0; nt < 4; ++nt) {
                accs[mt][nt] = __builtin_amdgcn_mfma_f32_16x16x32_bf16(af[mt], bs[nt], accs[mt][nt], 0, 0, 0);
                accp[mt][nt] = __builtin_amdgcn_mfma_f32_16x16x32_bf16(af[mt], bp[nt], accp[mt][nt], 0, 0, 0);
            }
        __syncthreads();
    }

    red[t] = dwpart;
    __syncthreads();
    if (t < 64) {
        float s = red[4*t] + red[4*t+1] + red[4*t+2] + red[4*t+3] + b_nw[0];
        float dv = 1.f / (1.f + __expf(-s));
        dw_l[t] = dv;
        aw_out[(size_t)b * 2 * NN + nb + t] = dv;
    }
    __syncthreads();

    #pragma unroll
    for (int mt = 0; mt < 2; ++mt) {
        #pragma unroll
        for (int nt = 0; nt < 4; ++nt) {
            const int e = wn*64 + nt*16 + l16;
            const float bsv = b_self[e];
            #pragma unroll
            for (int r = 0; r < 4; ++r) {
                const int nl = wm*32 + mt*16 + quad*4 + r;
                const size_t idx = (size_t)(n0 + nl) * DD + e;
                const float yv = dw_l[nl] * accp[mt][nt][r];
                const unsigned short ub = f2bf(yv);
                const float yvr = bf2f(ub);
                si_out[idx] = accs[mt][nt][r] + bsv - scl_l[nl] * pdm_l[nl] * yvr;
                ytl[e*72 + nl] = ub;
            }
        }
    }
    __syncthreads();
    {
        const int e = t >> 1, half = t & 1;
        const i32x4* src = (const i32x4*)&ytl[e*72 + half*32];
        i32x4 v0 = src[0], v1 = src[1], v2 = src[2], v3 = src[3];
        i32x4* dst = (i32x4*)(yT_out + (size_t)(b*DD + e) * NN + nb + half*32);
        dst[0] = v0; dst[1] = v1; dst[2] = v2; dst[3] = v3;
    }
}

// kernCB: FUSED C0 + B1. 60.7KB LDS phase-unioned -> 2 blocks/CU.
// C phase: acc = Ptilde @ yhat0; x = relu(sip0 + scale*acc) in registers ->
// xt4 (bf16, per-kk LDS) + dw partials. B phase: GEMMs from xt4 + staged
// bf16 weights; diag-folded si'1, yT1, aw1.
#define OFF_SCL   0u
#define OFF_PDM   256u
#define OFF_WNW   512u
#define OFF_DW    1024u
#define OFF_A     1280u
#define OFF_XT4   1280u
#define OFF_RED   (1280u + 16384u)
#define OFF_B     25856u
#define OFF_WST   25856u
#define OFF_WPT   (25856u + 8192u)
#define OFF_YTL   (25856u + 16384u)
#define SMEM_CB   60672u

__global__ __launch_bounds__(256) void kernCB(
    const unsigned* __restrict__ pk,
    const float* __restrict__ scale_g, const float* __restrict__ pdm_g,
    const unsigned short* __restrict__ yT0,
    float* si,                               // in: si'0 ; out: si'1 (same rows)
    const unsigned short* __restrict__ wsb, const unsigned short* __restrict__ wpb,
    const float* __restrict__ w_nw, const float* __restrict__ b_nw,
    const float* __restrict__ b_self,
    unsigned short* __restrict__ yT1,
    float* __restrict__ aw1)                 // aw + NN already applied
{
    __shared__ char smem[SMEM_CB];
    float*          scl_l = (float*)(smem + OFF_SCL);
    float*          pdm_l = (float*)(smem + OFF_PDM);
    float*          wnw_l = (float*)(smem + OFF_WNW);
    float*          dw_l  = (float*)(smem + OFF_DW);
    unsigned*       pPk   = (unsigned*)(smem + OFF_A);
    unsigned short* xt4   = (unsigned short*)(smem + OFF_XT4);
    float*          red   = (float*)(smem + OFF_RED);
    f32x4*          accL  = (f32x4*)(smem + OFF_B);       // [2][16][64]
    unsigned short* wst   = (unsigned short*)(smem + OFF_WST);
    unsigned short* wpt   = (unsigned short*)(smem + OFF_WPT);
    unsigned short* ytl   = (unsigned short*)(smem + OFF_YTL);

    const int t  = threadIdx.x;
    const int b  = blockIdx.x & 7;          // XCD-aware batch mapping
    const int i0 = (blockIdx.x >> 3) * 64;  // 0..1984
    const size_t rg0 = (size_t)b * NN + i0;

    #pragma unroll
    for (int r = 0; r < 4; ++r) {
        const int u   = r * 256 + t;
        const int row = u >> 4;
        const int wq  = (u & 15) * 4;
        i32x4 v = *(const i32x4*)(pk + (rg0 + row) * 64 + wq);
        *(i32x4*)&pPk[row * 68 + wq] = v;
    }
    if (t < 64)                   scl_l[t]      = scale_g[rg0 + t];
    else if (t < 128)             pdm_l[t-64]   = pdm_g[rg0 + t - 64];
    else                          wnw_l[t-128]  = w_nw[t-128];
    __syncthreads();

    const int wave = t >> 6, lane = t & 63;
    const int kh = wave >> 1, eh = wave & 1;
    const int quad = lane >> 4, l16 = lane & 15;
    const unsigned short* yTb = yT0 + (size_t)b * DD * NN;

    f32x4 acc[4][4] = {};
    #pragma unroll 4
    for (int ks = 0; ks < 32; ++ks) {
        const int kk = kh * 32 + ks;
        bf16x8 bfr[4];
        #pragma unroll
        for (int nt = 0; nt < 4; ++nt) {
            const int e = eh*64 + nt*16 + l16;
            bfr[nt] = *(const bf16x8*)(yTb + (size_t)e * NN + kk*32 + quad*8);
        }
        bf16x8 af[4];
        #pragma unroll
        for (int mt = 0; mt < 4; ++mt) {
            const unsigned w = pPk[(mt*16 + l16) * 68 + kk];
            const unsigned by = (w >> (quad * 8)) & 0xFFu;
            i32x4 ex;
            ex.x = (int)((((by &   1u) << 7) + ((by &   2u) << 22)) * 0x7Fu);
            ex.y = (int)((((by &   4u) << 5) + ((by &   8u) << 20)) * 0x7Fu);
            ex.z = (int)((((by &  16u) << 3) + ((by &  32u) << 18)) * 0x7Fu);
            ex.w = (int)((((by &  64u) << 1) + ((by & 128u) << 16)) * 0x7Fu);
            union { i32x4 i; bf16x8 h; } cv; cv.i = ex;
            af[mt] = cv.h;
        }
        #pragma unroll
        for (int mt = 0; mt < 4; ++mt)
            #pragma unroll
            for (int nt = 0; nt < 4; ++nt)
                acc[mt][nt] = __builtin_amdgcn_mfma_f32_16x16x32_bf16(af[mt], bfr[nt], acc[mt][nt], 0, 0, 0);
    }

    __syncthreads();                         // K-loops done; pPk dead
    if (kh == 1) {
        #pragma unroll
        for (int mt = 0; mt < 4; ++mt)
            #pragma unroll
            for (int nt = 0; nt < 4; ++nt)
                accL[(eh*16 + mt*4 + nt)*64 + lane] = acc[mt][nt];
    }
    __syncthreads();

    if (kh == 0) {
        #pragma unroll
        for (int mt = 0; mt < 4; ++mt) {
            float part[4] = {0.f, 0.f, 0.f, 0.f};
            #pragma unroll
            for (int nt = 0; nt < 4; ++nt) {
                f32x4 o = accL[(eh*16 + mt*4 + nt)*64 + lane];
                const int e = eh*64 + nt*16 + l16;
                const float wv = wnw_l[e];
                #pragma unroll
                for (int r = 0; r < 4; ++r) {
                    const int row = mt*16 + quad*4 + r;
                    const size_t idx = (rg0 + row) * DD + e;
                    float xv = si[idx] + scl_l[row] * (acc[mt][nt][r] + o[r]);
                    xv = fmaxf(xv, 0.f);
                    xt4[((e >> 5) * 64 + row) * 32 + (e & 31)] = f2bf(xv);
                    part[r] += xv * wv;
                }
            }
            #pragma unroll
            for (int r = 0; r < 4; ++r) {
                const int row = mt*16 + quad*4 + r;
                red[row * 32 + eh*16 + l16] = part[r];
            }
        }
    }
    __syncthreads();                         // accL dead after this

    if (t < 64) {
        float s = b_nw[0];
        #pragma unroll 8
        for (int c = 0; c < 32; ++c) s += red[t * 32 + c];
        float dv = 1.f / (1.f + __expf(-s));
        dw_l[t] = dv;
        aw1[(size_t)b * 2 * NN + i0 + t] = dv;
    }
    __syncthreads();

    const int wm = kh, wn = eh;
    const int we = t >> 1, wh = t & 1;

    f32x4 accs[2][4] = {}; f32x4 accp[2][4] = {};

    #pragma unroll
    for (int kk = 0; kk < 4; ++kk) {
        const int k0 = kk * 32;
        {
            const unsigned short* s1 = wsb + (size_t)we * DD + k0 + wh*16;
            const unsigned short* s2 = wpb + (size_t)we * DD + k0 + wh*16;
            i32x4 a0 = *(const i32x4*)s1;
            i32x4 a1 = *(const i32x4*)(s1 + 8);
            *(i32x4*)&wst[we*32 + wh*16]     = a0;
            *(i32x4*)&wst[we*32 + wh*16 + 8] = a1;
            i32x4 c0 = *(const i32x4*)s2;
            i32x4 c1 = *(const i32x4*)(s2 + 8);
            *(i32x4*)&wpt[we*32 + wh*16]     = c0;
            *(i32x4*)&wpt[we*32 + wh*16 + 8] = c1;
        }
        __syncthreads();
        bf16x8 af[2], bs[4], bp[4];
        #pragma unroll
        for (int mt = 0; mt < 2; ++mt)
            af[mt] = *(const bf16x8*)&xt4[(kk*64 + wm*32 + mt*16 + l16)*32 + quad*8];
        #pragma unroll
        for (int nt = 0; nt < 4; ++nt) {
            const int er = wn*64 + nt*16 + l16;
            bs[nt] = *(const bf16x8*)&wst[er*32 + quad*8];
            bp[nt] = *(const bf16x8*)&wpt[er*32 + quad*8];
        }
        #pragma unroll
        for (int mt = 0; mt < 2; ++mt)
            #pragma unroll
            for (int nt = 0; nt < 4; ++nt) {
                accs[mt][nt] = __builtin_amdgcn_mfma_f32_16x16x32_bf16(af[mt], bs[nt], accs[mt][nt], 0, 0, 0);
                accp[mt][nt] = __builtin_amdgcn_mfma_f32_16x16x32_bf16(af[mt], bp[nt], accp[mt][nt], 0, 0, 0);
            }
        __syncthreads();
    }

    #pragma unroll
    for (int mt = 0; mt < 2; ++mt) {
        #pragma unroll
        for (int nt = 0; nt < 4; ++nt) {
            const int e = wn*64 + nt*16 + l16;
            const float bsv = b_self[e];
            #pragma unroll
            for (int r = 0; r < 4; ++r) {
                const int nl = wm*32 + mt*16 + quad*4 + r;
                const size_t idx = (rg0 + nl) * DD + e;
                const float yv = dw_l[nl] * accp[mt][nt][r];
                const unsigned short ub = f2bf(yv);
                const float yvr = bf2f(ub);
                si[idx] = accs[mt][nt][r] + bsv - scl_l[nl] * pdm_l[nl] * yvr;
                ytl[e*72 + nl] = ub;
            }
        }
    }
    __syncthreads();
    {
        const int e = t >> 1, half = t & 1;
        const i32x4* src = (const i32x4*)&ytl[e*72 + half*32];
        i32x4 v0 = src[0], v1 = src[1], v2 = src[2], v3 = src[3];
        i32x4* dst = (i32x4*)(yT1 + (size_t)(b*DD + e) * NN + i0 + half*32);
        dst[0] = v0; dst[1] = v1; dst[2] = v2; dst[3] = v3;
    }
}

// kernC4: final C — x_out = relu(si' + scale*agg).
__global__ __launch_bounds__(256) void kernC4(
    const unsigned* __restrict__ pk,
    const float* __restrict__ scale_g,
    const unsigned short* __restrict__ yT,
    const float* __restrict__ sip,
    float* __restrict__ x_out)
{
    __shared__ unsigned pPk[64 * 68];
    __shared__ float scale_l[64];
    __shared__ f32x4 accL[2][16][64];

    const int t  = threadIdx.x;
    const int b  = blockIdx.x & 7;
    const int i0 = (blockIdx.x >> 3) * 64;
    const size_t rg0 = (size_t)b * NN + i0;

    #pragma unroll
    for (int r = 0; r < 4; ++r) {
        const int u   = r * 256 + t;
        const int row = u >> 4;
        const int wq  = (u & 15) * 4;
        i32x4 v = *(const i32x4*)(pk + (rg0 + row) * 64 + wq);
        *(i32x4*)&pPk[row * 68 + wq] = v;
    }
    if (t < 64) scale_l[t] = scale_g[rg0 + t];
    __syncthreads();

    const int wave = t >> 6, lane = t & 63;
    const int kh = wave >> 1, eh = wave & 1;
    const int quad = lane >> 4, l16 = lane & 15;
    const unsigned short* yTb = yT + (size_t)b * DD * NN;

    f32x4 acc[4][4] = {};

    #pragma unroll 4
    for (int ks = 0; ks < 32; ++ks) {
        const int kk = kh * 32 + ks;
        bf16x8 bfr[4];
        #pragma unroll
        for (int nt = 0; nt < 4; ++nt) {
            const int e = eh*64 + nt*16 + l16;
            bfr[nt] = *(const bf16x8*)(yTb + (size_t)e * NN + kk*32 + quad*8);
        }
        bf16x8 af[4];
        #pragma unroll
        for (int mt = 0; mt < 4; ++mt) {
            const unsigned w = pPk[(mt*16 + l16) * 68 + kk];
            const unsigned by = (w >> (quad * 8)) & 0xFFu;
            i32x4 ex;
            ex.x = (int)((((by &   1u) << 7) + ((by &   2u) << 22)) * 0x7Fu);
            ex.y = (int)((((by &   4u) << 5) + ((by &   8u) << 20)) * 0x7Fu);
            ex.z = (int)((((by &  16u) << 3) + ((by &  32u) << 18)) * 0x7Fu);
            ex.w = (int)((((by &  64u) << 1) + ((by & 128u) << 16)) * 0x7Fu);
            union { i32x4 i; bf16x8 h; } cv; cv.i = ex;
            af[mt] = cv.h;
        }
        #pragma unroll
        for (int mt = 0; mt < 4; ++mt)
            #pragma unroll
            for (int nt = 0; nt < 4; ++nt)
                acc[mt][nt] = __builtin_amdgcn_mfma_f32_16x16x32_bf16(af[mt], bfr[nt], acc[mt][nt], 0, 0, 0);
    }

    __syncthreads();
    if (kh == 1) {
        #pragma unroll
        for (int mt = 0; mt < 4; ++mt)
            #pragma unroll
            for (int nt = 0; nt < 4; ++nt)
                accL[eh][mt*4 + nt][lane] = acc[mt][nt];
    }
    __syncthreads();
    if (kh == 0) {
        #pragma unroll
        for (int mt = 0; mt < 4; ++mt) {
            #pragma unroll
            for (int nt = 0; nt < 4; ++nt) {
                f32x4 o = accL[eh][mt*4 + nt][lane];
                const int e = eh*64 + nt*16 + l16;
                #pragma unroll
                for (int r = 0; r < 4; ++r) {
                    const int row = mt*16 + quad*4 + r;
                    const size_t idx = (rg0 + row) * DD + e;
                    float v = sip[idx] + scale_l[row] * (acc[mt][nt][r] + o[r]);
                    x_out[idx] = fmaxf(v, 0.f);
                }
            }
        }
    }
}

extern "C" void kernel_launch(void* const* d_in, const int* in_sizes, int n_in,
                              void* d_out, int out_size, void* d_ws, size_t ws_size,
                              hipStream_t stream) {
    const float* node   = (const float*)d_in[0];
    const int*   mask   = (const int*)  d_in[1];
    const int*   punct  = (const int*)  d_in[2];
    const float* w_nw   = (const float*)d_in[3];
    const float* b_nw   = (const float*)d_in[4];
    const float* w_self = (const float*)d_in[5];
    const float* b_self = (const float*)d_in[6];
    const float* w_punct= (const float*)d_in[7];

    float* xout = (float*)d_out;
    float* aw   = xout + (size_t)BB * NN * DD;

    char* w = (char*)d_ws;
    float*          si   = (float*)w;                               // 8 MB (si')
    unsigned short* yT0  = (unsigned short*)(w + (12u << 20));      // 4 MB
    unsigned*       pk   = (unsigned*)(w + (16u << 20));            // 4 MB
    float*          scl  = (float*)(w + (20u << 20));               // 64 KB
    float*          pdm  = (float*)(w + (20u << 20) + (64u << 10)); // 64 KB
    unsigned short* wsb  = (unsigned short*)(w + (21u << 20));      // 32 KB
    unsigned short* wpb  = (unsigned short*)(w + (21u << 20) + (32u << 10)); // 32 KB
    unsigned short* yT1  = (unsigned short*)(w + (24u << 20));      // 4 MB

    kernP3<<<dim3(2064), dim3(256), 0, stream>>>(punct, mask, w_self, w_punct,
                                                 pk, scl, pdm, wsb, wpb);
    kernB <<<dim3(256),  dim3(256), 0, stream>>>(node, wsb, wpb, w_nw, b_nw,
                                                 b_self, scl, pdm, si, yT0, aw);
    kernCB<<<dim3(256),  dim3(256), 0, stream>>>(pk, scl, pdm, yT0, si,
                                                 wsb, wpb, w_nw, b_nw, b_self,
                                                 yT1, aw + NN);
    kernC4<<<dim3(256),  dim3(256), 0, stream>>>(pk, scl, yT1, si, xout);
}